// Round 6
// baseline (512.700 us; speedup 1.0000x reference)
//
#include <hip/hip_runtime.h>
#include <hip/hip_bf16.h>

#define NROWS 8192
#define HALFN 4096
#define DIMK  128
#define JC    32              // j-chunks
#define LJ    (NROWS / JC)    // 256 columns per chunk
#define TJ    32              // columns per LDS tile
#define NT    (LJ / TJ)       // 8 tiles per block
#define BAND  256             // rows per block (4 waves x 64)
#define NBAND (NROWS / BAND)  // 32

typedef __attribute__((ext_vector_type(8))) short short8;
typedef __attribute__((ext_vector_type(4))) float f32x4;

// znb is pre-scaled by sqrt(2*log2(e)):  dot(znb_a, znb_b) = sim * log2(e)
// => exp(sim) = 2^dot, and pos-term sim = dot * ln2.
#define SQRT_EXPSCALE 1.6986436f      // sqrt(2*log2(e))
#define LN2F          0.69314718f

static __device__ __forceinline__ float bf2f(unsigned short u) {
    union { float f; unsigned int i; } x;
    x.i = ((unsigned int)u) << 16;
    return x.f;
}

// ---- K1: normalize+scale rows -> bf16 [8192][128]; zero S and out ----------
__global__ __launch_bounds__(256) void k_norm(const float* __restrict__ zi,
                                              const float* __restrict__ zj,
                                              unsigned short* __restrict__ znb,
                                              float* __restrict__ S,
                                              float* __restrict__ out) {
    if (threadIdx.x < 4) S[blockIdx.x * 4 + threadIdx.x] = 0.f;
    if (blockIdx.x == 0 && threadIdx.x == 0) out[0] = 0.f;

    const int lane = threadIdx.x & 63;
    const int wave = threadIdx.x >> 6;
    const int row  = blockIdx.x * 4 + wave;
    const float* src = (row < HALFN) ? (zi + (size_t)row * DIMK)
                                     : (zj + (size_t)(row - HALFN) * DIMK);
    float2 v = *reinterpret_cast<const float2*>(src + lane * 2);
    float ss = v.x * v.x + v.y * v.y;
    #pragma unroll
    for (int m = 1; m < 64; m <<= 1) ss += __shfl_xor(ss, m);
    float rn = rsqrtf(ss) * SQRT_EXPSCALE;
    __hip_bfloat16 ha = __float2bfloat16(v.x * rn);
    __hip_bfloat16 hb = __float2bfloat16(v.y * rn);
    ushort2 o;
    o.x = *reinterpret_cast<unsigned short*>(&ha);
    o.y = *reinterpret_cast<unsigned short*>(&hb);
    *reinterpret_cast<ushort2*>(znb + (size_t)row * DIMK + lane * 2) = o;
}

// ---- K2: fused sim + exp row-sum, LDS-staged B shared by 4 waves -----------
// grid = NBAND*JC = 1024 blocks, 256 threads. Each wave owns 64 rows
// (4 x 16-row fragments, A resident) and all waves share 32-col B tiles
// double-buffered in LDS (XOR-swizzled, written and read with same involution).
__global__ __launch_bounds__(256, 4) void k_main(const unsigned short* __restrict__ znb,
                                                 float* __restrict__ S) {
    __shared__ unsigned char lds[2][TJ * 256];   // 2 x 8 KB

    const int tid  = threadIdx.x;
    const int lane = tid & 63;
    const int wave = tid >> 6;
    const int band = blockIdx.x & (NBAND - 1);
    const int jc   = blockIdx.x >> 5;            // / NBAND==32
    const int row0 = band * BAND + wave * 64;
    const int jbase = jc * LJ;

    const int rsel = lane & 15;   // fragment row/col selector
    const int g    = lane >> 4;   // k-group

    // A fragments: rows row0..row0+63; lane: row=row0+rf*16+rsel, k=kk*32+g*8
    const unsigned short* arow = znb + (size_t)(row0 + rsel) * DIMK + g * 8;
    short8 afr[4][4];
    #pragma unroll
    for (int rf = 0; rf < 4; ++rf)
        #pragma unroll
        for (int kk = 0; kk < 4; ++kk)
            afr[rf][kk] = *reinterpret_cast<const short8*>(arow + rf * 16 * DIMK + kk * 32);

    float sacc[4][4];
    #pragma unroll
    for (int rf = 0; rf < 4; ++rf)
        #pragma unroll
        for (int r = 0; r < 4; ++r) sacc[rf][r] = 0.f;

    // Staging: thread covers tile granules G=tid (rows 0-15) and G=tid+256
    // (rows 16-31); granule (r,c) -> LDS slot (r, c ^ (r&7)) [T2 involution].
    const int r_a = tid >> 4;            // 0..15
    const int c_a = tid & 15;
    const int r_b = r_a + 16;            // 16..31
    const unsigned short* gA = znb + (size_t)(jbase + r_a) * DIMK + c_a * 8;
    const unsigned short* gB = znb + (size_t)(jbase + r_b) * DIMK + c_a * 8;
    const int ldsA = r_a * 256 + ((c_a ^ (r_a & 7)) << 4);
    const int ldsB = r_b * 256 + ((c_a ^ (r_b & 7)) << 4);

    {   // prologue: stage tile 0 into buf 0
        short8 v0 = *reinterpret_cast<const short8*>(gA);
        short8 v1 = *reinterpret_cast<const short8*>(gB);
        *reinterpret_cast<short8*>(&lds[0][ldsA]) = v0;
        *reinterpret_cast<short8*>(&lds[0][ldsB]) = v1;
    }

    int cur = 0;
    for (int t = 0; t < NT; ++t) {
        short8 v0, v1;
        if (t + 1 < NT) {   // issue next-tile global loads early (T14)
            v0 = *reinterpret_cast<const short8*>(gA + (size_t)(t + 1) * TJ * DIMK);
            v1 = *reinterpret_cast<const short8*>(gB + (size_t)(t + 1) * TJ * DIMK);
        }
        __syncthreads();    // buf[cur] writes visible; prior reads of buf[cur^1] done

        const int j0 = jbase + t * TJ;
        #pragma unroll
        for (int jf = 0; jf < 2; ++jf) {
            short8 bfr[4];
            #pragma unroll
            for (int kk = 0; kk < 4; ++kk) {
                const int slot = (kk * 4 + g) ^ (rsel & 7);
                bfr[kk] = *reinterpret_cast<const short8*>(
                    &lds[cur][(jf * 16 + rsel) * 256 + slot * 16]);
            }
            #pragma unroll
            for (int rf = 0; rf < 4; ++rf) {
                f32x4 c = {0.f, 0.f, 0.f, 0.f};
                #pragma unroll
                for (int kk = 0; kk < 4; ++kk)
                    c = __builtin_amdgcn_mfma_f32_16x16x32_bf16(afr[rf][kk], bfr[kk], c, 0, 0, 0);
                // C layout (m89): col = lane&15, row = (lane>>4)*4 + reg
                if (__builtin_expect(j0 + jf * 16 == row0 + rf * 16, 0)) {
                    #pragma unroll
                    for (int r = 0; r < 4; ++r) {
                        float e = exp2f(c[r]);
                        if (rsel == g * 4 + r) e = 0.f;   // mask j == i
                        sacc[rf][r] += e;
                    }
                } else {
                    #pragma unroll
                    for (int r = 0; r < 4; ++r)
                        sacc[rf][r] += exp2f(c[r]);
                }
            }
        }
        if (t + 1 < NT) {   // write next tile late, after compute (T14)
            *reinterpret_cast<short8*>(&lds[cur ^ 1][ldsA]) = v0;
            *reinterpret_cast<short8*>(&lds[cur ^ 1][ldsB]) = v1;
        }
        cur ^= 1;
    }

    // Reduce across the 16 lanes of each k-group (16 cols of the same 4 rows)
    #pragma unroll
    for (int rf = 0; rf < 4; ++rf)
        #pragma unroll
        for (int r = 0; r < 4; ++r) {
            float v = sacc[rf][r];
            v += __shfl_xor(v, 1);
            v += __shfl_xor(v, 2);
            v += __shfl_xor(v, 4);
            v += __shfl_xor(v, 8);
            sacc[rf][r] = v;
        }
    if (rsel == 0) {
        #pragma unroll
        for (int rf = 0; rf < 4; ++rf)
            #pragma unroll
            for (int r = 0; r < 4; ++r)
                atomicAdd(&S[row0 + rf * 16 + g * 4 + r], sacc[rf][r]);
    }
}

// ---- K3: per-row log(S) - pos, atomic accumulate loss ----------------------
__global__ __launch_bounds__(256) void k_rowterm(const unsigned short* __restrict__ znb,
                                                 const float* __restrict__ S,
                                                 float* __restrict__ out) {
    __shared__ float red[16];
    const int lane = threadIdx.x & 63;
    const int wave = threadIdx.x >> 6;
    const int rsel = lane & 15;
    const int g    = lane >> 4;
    const int row  = blockIdx.x * 16 + wave * 4 + g;
    const int p    = (row + HALFN) & (NROWS - 1);

    short8 a = *reinterpret_cast<const short8*>(znb + (size_t)row * DIMK + rsel * 8);
    short8 b = *reinterpret_cast<const short8*>(znb + (size_t)p   * DIMK + rsel * 8);
    float d = 0.f;
    #pragma unroll
    for (int i = 0; i < 8; ++i)
        d += bf2f((unsigned short)a[i]) * bf2f((unsigned short)b[i]);
    #pragma unroll
    for (int m = 1; m < 16; m <<= 1) d += __shfl_xor(d, m);
    if (rsel == 0) red[wave * 4 + g] = __logf(S[row]) - d * LN2F;
    __syncthreads();
    if (threadIdx.x < 16) {
        float v = red[threadIdx.x];
        #pragma unroll
        for (int m = 1; m < 16; m <<= 1) v += __shfl_xor(v, m);
        if (threadIdx.x == 0) atomicAdd(out, v * (1.0f / (float)NROWS));
    }
}

extern "C" void kernel_launch(void* const* d_in, const int* in_sizes, int n_in,
                              void* d_out, int out_size, void* d_ws, size_t ws_size,
                              hipStream_t stream) {
    const float* zi = (const float*)d_in[0];
    const float* zj = (const float*)d_in[1];
    float* out = (float*)d_out;
    char* ws = (char*)d_ws;

    unsigned short* znb = (unsigned short*)ws;                      // 2 MB
    float*          S   = (float*)(ws + (size_t)NROWS * DIMK * 2);  // 32 KB

    k_norm   <<<NROWS / 4, 256, 0, stream>>>(zi, zj, znb, S, out);
    k_main   <<<NBAND * JC, 256, 0, stream>>>(znb, S);
    k_rowterm<<<NROWS / 16, 256, 0, stream>>>(znb, S, out);
}

// Round 7
// 105.033 us; speedup vs baseline: 4.8813x; 4.8813x over previous
//
#include <hip/hip_runtime.h>
#include <hip/hip_bf16.h>

#define NROWS 8192
#define HALFN 4096
#define DIMK  128
#define JC    32              // j-chunks
#define LJ    (NROWS / JC)    // 256 columns per chunk
#define TJ    32              // columns per LDS tile
#define NT    (LJ / TJ)       // 8 tiles per block
#define BAND  256             // rows per block (8 waves x 32)
#define NBAND (NROWS / BAND)  // 32

typedef __attribute__((ext_vector_type(8))) short short8;
typedef __attribute__((ext_vector_type(4))) float f32x4;

// znb is pre-scaled by sqrt(2*log2(e)):  dot(znb_a, znb_b) = sim * log2(e)
// => exp(sim) = 2^dot, and pos-term sim = dot * ln2.
#define SQRT_EXPSCALE 1.6986436f      // sqrt(2*log2(e))
#define LN2F          0.69314718f

static __device__ __forceinline__ float bf2f(unsigned short u) {
    union { float f; unsigned int i; } x;
    x.i = ((unsigned int)u) << 16;
    return x.f;
}

// ---- K1: normalize+scale rows -> bf16 [8192][128]; zero S and out ----------
__global__ __launch_bounds__(256) void k_norm(const float* __restrict__ zi,
                                              const float* __restrict__ zj,
                                              unsigned short* __restrict__ znb,
                                              float* __restrict__ S,
                                              float* __restrict__ out) {
    if (threadIdx.x < 4) S[blockIdx.x * 4 + threadIdx.x] = 0.f;
    if (blockIdx.x == 0 && threadIdx.x == 0) out[0] = 0.f;

    const int lane = threadIdx.x & 63;
    const int wave = threadIdx.x >> 6;
    const int row  = blockIdx.x * 4 + wave;
    const float* src = (row < HALFN) ? (zi + (size_t)row * DIMK)
                                     : (zj + (size_t)(row - HALFN) * DIMK);
    float2 v = *reinterpret_cast<const float2*>(src + lane * 2);
    float ss = v.x * v.x + v.y * v.y;
    #pragma unroll
    for (int m = 1; m < 64; m <<= 1) ss += __shfl_xor(ss, m);
    float rn = rsqrtf(ss) * SQRT_EXPSCALE;
    __hip_bfloat16 ha = __float2bfloat16(v.x * rn);
    __hip_bfloat16 hb = __float2bfloat16(v.y * rn);
    ushort2 o;
    o.x = *reinterpret_cast<unsigned short*>(&ha);
    o.y = *reinterpret_cast<unsigned short*>(&hb);
    *reinterpret_cast<ushort2*>(znb + (size_t)row * DIMK + lane * 2) = o;
}

// ---- K2: fused sim + exp row-sum; LDS-staged B shared by 8 waves -----------
// grid = NBAND*JC = 1024 blocks x 512 threads. Each wave owns 32 rows
// (2 x 16-row fragments, A resident: 32 VGPR — the shape R2 proved the
// compiler holds). 32-col B tiles double-buffered in LDS, XOR-swizzled.
// NOTE: plain launch_bounds — the ",4" min-waves arg forced a 64-VGPR cap
// and catastrophic spill in R3/R6 (VGPR=64, WRITE_SIZE 800 MB).
__global__ __launch_bounds__(512) void k_main(const unsigned short* __restrict__ znb,
                                              float* __restrict__ S) {
    __shared__ unsigned char lds[2][TJ * 256];   // 2 x 8 KB

    const int tid  = threadIdx.x;
    const int lane = tid & 63;
    const int wave = tid >> 6;
    const int band = blockIdx.x & (NBAND - 1);
    const int jc   = blockIdx.x >> 5;            // / NBAND==32
    const int row0 = band * BAND + wave * 32;    // wave's first row
    const int jbase = jc * LJ;

    const int rsel = lane & 15;   // fragment row/col selector
    const int g    = lane >> 4;   // k-group

    // A fragments: rows row0..row0+31; lane: row=row0+rf*16+rsel, k=kk*32+g*8
    const unsigned short* arow = znb + (size_t)(row0 + rsel) * DIMK + g * 8;
    short8 afr[2][4];
    #pragma unroll
    for (int rf = 0; rf < 2; ++rf)
        #pragma unroll
        for (int kk = 0; kk < 4; ++kk)
            afr[rf][kk] = *reinterpret_cast<const short8*>(arow + rf * 16 * DIMK + kk * 32);

    float sacc[2][4];
    #pragma unroll
    for (int rf = 0; rf < 2; ++rf)
        #pragma unroll
        for (int r = 0; r < 4; ++r) sacc[rf][r] = 0.f;

    // Staging: one 16B granule per thread per tile (512 x 16B = 8 KB).
    // Granule (r,c) -> LDS slot (r, c ^ (r&7)) [T2 involution].
    const int r_s = tid >> 4;            // 0..31
    const int c_s = tid & 15;
    const unsigned short* gsrc = znb + (size_t)(jbase + r_s) * DIMK + c_s * 8;
    const int ldsoff = r_s * 256 + ((c_s ^ (r_s & 7)) << 4);

    {   // prologue: stage tile 0 into buf 0
        short8 v0 = *reinterpret_cast<const short8*>(gsrc);
        *reinterpret_cast<short8*>(&lds[0][ldsoff]) = v0;
    }

    int cur = 0;
    for (int t = 0; t < NT; ++t) {
        short8 v0;
        if (t + 1 < NT)    // issue next-tile global load early (T14)
            v0 = *reinterpret_cast<const short8*>(gsrc + (size_t)(t + 1) * TJ * DIMK);
        __syncthreads();   // buf[cur] writes visible; prior buf[cur^1] reads done

        const int j0 = jbase + t * TJ;
        #pragma unroll
        for (int jf = 0; jf < 2; ++jf) {
            short8 bfr[4];
            #pragma unroll
            for (int kk = 0; kk < 4; ++kk) {
                const int slot = (kk * 4 + g) ^ (rsel & 7);
                bfr[kk] = *reinterpret_cast<const short8*>(
                    &lds[cur][(jf * 16 + rsel) * 256 + slot * 16]);
            }
            #pragma unroll
            for (int rf = 0; rf < 2; ++rf) {
                f32x4 c = {0.f, 0.f, 0.f, 0.f};
                #pragma unroll
                for (int kk = 0; kk < 4; ++kk)
                    c = __builtin_amdgcn_mfma_f32_16x16x32_bf16(afr[rf][kk], bfr[kk], c, 0, 0, 0);
                // C layout (m89): n-col = lane&15, m-row = (lane>>4)*4 + reg
                if (__builtin_expect(j0 + jf * 16 == row0 + rf * 16, 0)) {
                    #pragma unroll
                    for (int r = 0; r < 4; ++r) {
                        float e = exp2f(c[r]);
                        if (rsel == g * 4 + r) e = 0.f;   // mask j == i
                        sacc[rf][r] += e;
                    }
                } else {
                    #pragma unroll
                    for (int r = 0; r < 4; ++r)
                        sacc[rf][r] += exp2f(c[r]);
                }
            }
        }
        if (t + 1 < NT)    // write next tile late, after compute (T14)
            *reinterpret_cast<short8*>(&lds[cur ^ 1][ldsoff]) = v0;
        cur ^= 1;
    }

    // Reduce across the 16 lanes of each k-group (16 cols of the same 4 rows)
    #pragma unroll
    for (int rf = 0; rf < 2; ++rf)
        #pragma unroll
        for (int r = 0; r < 4; ++r) {
            float v = sacc[rf][r];
            v += __shfl_xor(v, 1);
            v += __shfl_xor(v, 2);
            v += __shfl_xor(v, 4);
            v += __shfl_xor(v, 8);
            sacc[rf][r] = v;
        }
    if (rsel == 0) {
        #pragma unroll
        for (int rf = 0; rf < 2; ++rf)
            #pragma unroll
            for (int r = 0; r < 4; ++r)
                atomicAdd(&S[row0 + rf * 16 + g * 4 + r], sacc[rf][r]);
    }
}

// ---- K3: per-row log(S) - pos, atomic accumulate loss ----------------------
__global__ __launch_bounds__(256) void k_rowterm(const unsigned short* __restrict__ znb,
                                                 const float* __restrict__ S,
                                                 float* __restrict__ out) {
    __shared__ float red[16];
    const int lane = threadIdx.x & 63;
    const int wave = threadIdx.x >> 6;
    const int rsel = lane & 15;
    const int g    = lane >> 4;
    const int row  = blockIdx.x * 16 + wave * 4 + g;
    const int p    = (row + HALFN) & (NROWS - 1);

    short8 a = *reinterpret_cast<const short8*>(znb + (size_t)row * DIMK + rsel * 8);
    short8 b = *reinterpret_cast<const short8*>(znb + (size_t)p   * DIMK + rsel * 8);
    float d = 0.f;
    #pragma unroll
    for (int i = 0; i < 8; ++i)
        d += bf2f((unsigned short)a[i]) * bf2f((unsigned short)b[i]);
    #pragma unroll
    for (int m = 1; m < 16; m <<= 1) d += __shfl_xor(d, m);
    if (rsel == 0) red[wave * 4 + g] = __logf(S[row]) - d * LN2F;
    __syncthreads();
    if (threadIdx.x < 16) {
        float v = red[threadIdx.x];
        #pragma unroll
        for (int m = 1; m < 16; m <<= 1) v += __shfl_xor(v, m);
        if (threadIdx.x == 0) atomicAdd(out, v * (1.0f / (float)NROWS));
    }
}

extern "C" void kernel_launch(void* const* d_in, const int* in_sizes, int n_in,
                              void* d_out, int out_size, void* d_ws, size_t ws_size,
                              hipStream_t stream) {
    const float* zi = (const float*)d_in[0];
    const float* zj = (const float*)d_in[1];
    float* out = (float*)d_out;
    char* ws = (char*)d_ws;

    unsigned short* znb = (unsigned short*)ws;                      // 2 MB
    float*          S   = (float*)(ws + (size_t)NROWS * DIMK * 2);  // 32 KB

    k_norm   <<<NROWS / 4, 256, 0, stream>>>(zi, zj, znb, S, out);
    k_main   <<<NBAND * JC, 512, 0, stream>>>(znb, S);
    k_rowterm<<<NROWS / 16, 256, 0, stream>>>(znb, S, out);
}